// Round 7
// baseline (92.639 us; speedup 1.0000x reference)
//
#include <hip/hip_runtime.h>
#include <hip/hip_bf16.h>
#include <stdint.h>

// X-ray forward projection. Volume 128^3 fp32, detector 179x179, 10 views.
// Inputs fp32/int32: I_rec [1,1,128,128,128], poses [50,3], idx [10].
// Output fp32 flat: projections [10,179,179] then idx [10] as float.
//
// Geometry: vol[c][y][a], c = spatial_x+63.5, y index = plane p, a = spatial_z+63.5.
// Sampled y at plane p is exactly p-0.5 => ty=0.5:
//   contribution(p) = 0.5*(bilin(slice p-1) + bilin(slice p)) = 0.5*bilin(PS[p])
// Ray linear in p: c(p)=cb+p*sx, a(p)=ab+p*sz;  weight dxw = dist(Pd,E)/ey.
//
// Kept: row-interleaved PS (IL word = {row ci}<<16 | {row ci-1}; ONE uint2
// load/step gives all 4 corners), per-wave LDS c-table (broadcast ds_read_b64
// per step), 2-deep batch-8 pipeline (R15), grid 3x90x10 x 128thr.
// Fixed floor: harness 0xAA ws re-poison ~44.4us.
//
// DIAGNOSIS (R14-R18): VALU-issue-bound. 152 cyc/wave-step = ~17 VALU x 2cyc
// x 4 resident waves. R18's med3/fract peephole was ~no-op (compiler already
// fuses those) -> need STRUCTURAL VALU cuts.
//
// R19: (a) IL switched bf16 -> f16 (same 16-bit footprint, MORE mantissa);
// c-blend becomes v_dot2_f32_f16 (__builtin_amdgcn_fdot2): the c-table now
// stores a pre-packed half2 {1-tc, tc} (packed once per p, wave-uniform),
// CONSUME = 2 fdot2 + sub + fma + add = 5 VALU (was 10: 2 shifts + 2 ands +
// 2 subs + 2 fma + sub + fma). (b) table offset stored in BYTES -> per-step
// address = one v_lshl_add_u32 (t.y + (a0<<2)) feeding a saddr-form load.
// Per-step VALU ~17 -> ~11.
// R19b: fix clang type clash (cvt_pkrtz returns __fp16x2): pack tc manually
// via f16bits<<16|f16bits in the cold table-build; hot loop unchanged.

#define DVOL   128
#define RES    179
#define NPROJ  10
#define OUT_PROJ (NPROJ * RES * RES)
#define BATCH  8

#define IL_A   132                    // word cols: ai in [0,132); col a = ai-1
#define IL_C   130                    // word rows: word ci holds padded rows (ci-1, ci)
#define IL_SLAB (IL_C * IL_A)         // 17160 words per p-slab
#define IL_TOT  (DVOL * IL_SLAB)      // 2,196,480 words = 8.79 MB

typedef _Float16 half2_t __attribute__((ext_vector_type(2)));

__device__ __forceinline__ uint32_t f16bits(float v) {
    union { _Float16 h; unsigned short s; } u;
    u.h = (_Float16)v;                 // RNE
    return (uint32_t)u.s;
}
__device__ __forceinline__ half2_t ash2(uint32_t u) {
    union { uint32_t u; half2_t h; } x; x.u = u; return x.h;
}
__device__ __forceinline__ float asf(uint32_t u) { return __uint_as_float(u); }

// ---- IL builder, running-register sweep: word w = pack(f16[c=w], f16[c=w-1]).
// grid (8 word-ranges, 128 p), 128 threads = cols a 0..127 (ai = a+1).
__global__ __launch_bounds__(128) void pad_kernel(const float* __restrict__ vol,
                                                  uint32_t* __restrict__ il) {
    const int q = blockIdx.x;             // 0..7
    const int p = blockIdx.y;             // 0..127
    const int a = threadIdx.x;            // 0..127 -> ai = a+1
    const int wlo = q * 17;
    const int whi = min(130, wlo + 17);
    uint32_t* slab = il + p * IL_SLAB;

    uint32_t prev = 0;
    {   // c = wlo-1 (row feeding word wlo's low half)
        const int c = wlo - 1;
        if (c >= 0 && c < 128) {
            const float* src = vol + (c << 14) + (p << 7) + a;
            float v = src[0];
            if (p >= 1) v += src[-128];
            prev = f16bits(v);
        }
    }
    #pragma unroll 2
    for (int c = wlo; c < whi; ++c) {     // word w = c
        uint32_t cur = 0;
        if (c < 128) {
            const float* src = vol + (c << 14) + (p << 7) + a;
            float v = src[0];
            if (p >= 1) v += src[-128];
            cur = f16bits(v);
        }
        slab[c * IL_A + (a + 1)] = (cur << 16) | prev;
        prev = cur;
    }
    // boundary cols ai in {0,129,130,131} are zero words
    for (int b = a; b < (whi - wlo) * 4; b += 128) {
        const int w  = wlo + (b >> 2);
        const int bi = b & 3;
        const int ai = (bi == 0) ? 0 : (128 + bi);   // 0,129,130,131
        slab[w * IL_A + ai] = 0u;
    }
}

__device__ __forceinline__ void axis_interval(float base, float slope, float lo, float hi,
                                              float& t0, float& t1) {
    if (fabsf(slope) < 1e-9f) {
        const bool in = (base >= lo && base <= hi);
        t0 = in ? -1e30f : 1e30f;
        t1 = in ?  1e30f : -1e30f;
    } else {
        const float inv = 1.0f / slope;
        const float a = (lo - base) * inv;
        const float b = (hi - base) * inv;
        t0 = fminf(a, b);
        t1 = fmaxf(a, b);
    }
}

__device__ __forceinline__ int wave_imin(int v) {
    #pragma unroll
    for (int o = 32; o; o >>= 1) v = min(v, __shfl_xor(v, o, 64));
    return v;
}
__device__ __forceinline__ int wave_imax(int v) {
    #pragma unroll
    for (int o = 32; o; o >>= 1) v = max(v, __shfl_xor(v, o, 64));
    return v;
}

// Issue: table read (tcpk + byte-offset) + a-side addr (fma, med3, fract,
// cvt, lshl_add) + global uint2 load. af pre-biased +1 => [0,129].
#define ISSUE(tp_, ta_, w_, b_) do {                                          \
    const int base_ = (b_) * BATCH;                                           \
    const float afb_ = fmaf((float)base_, sz, af0);                           \
    _Pragma("unroll")                                                         \
    for (int k = 0; k < BATCH; ++k) {                                         \
        const uint2 t = tab[wid][base_ + k];        /* broadcast ds_read */   \
        tp_[k] = t.x;                               /* packed {1-tc, tc} */   \
        const float af1 = __builtin_amdgcn_fmed3f(                            \
            fmaf((float)k, sz, afb_), 0.0f, 129.0f);                          \
        ta_[k] = __builtin_amdgcn_fractf(af1);                                \
        const uint32_t off = t.y + (((uint32_t)(int)af1) << 2);  /* bytes */  \
        w_[k] = *(const uint2*)((const char*)il + off);                       \
    }                                                                         \
} while (0)

// Consume: 2x v_dot2_f32_f16 (c-blend) + a-blend. 5 VALU/step.
#define CONSUME(tp_, ta_, w_) do {                                            \
    _Pragma("unroll")                                                         \
    for (int k = 0; k < BATCH; ++k) {                                         \
        const half2_t tp = ash2(tp_[k]);                                      \
        const float hx = __builtin_amdgcn_fdot2(ash2(w_[k].x), tp, 0.0f, false);\
        const float hy = __builtin_amdgcn_fdot2(ash2(w_[k].y), tp, 0.0f, false);\
        acc += fmaf(ta_[k], hy - hx, hx);                                     \
    }                                                                         \
} while (0)

__global__ __launch_bounds__(128) void proj_fast(
    const uint32_t* __restrict__ il,  // IL [128][130][132] packed f16 pairs
    const float* __restrict__ poses,  // [50,3]
    const int* __restrict__ idx,      // [10]
    float* __restrict__ out)          // [10,179,179] + [10] tail
{
    // per-wave c-side table: {packed half2 {1-tc,tc}, byte offset sans a-term}
    __shared__ uint2 tab[2][DVOL];

    const int lane = threadIdx.x & 63;
    const int wid  = threadIdx.x >> 6;      // 2 waves/block
    int gj = blockIdx.x * 64 + lane;        // detector col -> contiguous a
    int gi = blockIdx.y * 2 + wid;          // detector row (wave-uniform)
    const int j = blockIdx.z;

    if (blockIdx.x == 0 && blockIdx.y == 0 && j == 0 && threadIdx.x < NPROJ)
        out[OUT_PROJ + threadIdx.x] = (float)idx[threadIdx.x];

    const bool store_ok = (gi < RES) && (gj < RES);
    gi = min(gi, RES - 1);   // stays wave-uniform
    gj = min(gj, RES - 1);   // dup lanes compute duplicates, store masked

    const int pid = idx[j];
    const float ex = poses[pid * 3 + 0];
    const float ey = poses[pid * 3 + 1];    // [256,384)
    const float ez = poses[pid * 3 + 2];

    const float pdx = (float)gi - 89.5f;
    const float pdz = (float)gj - 89.5f;

    const float inv_ey = 1.0f / ey;
    const float sx = (ex - pdx) * inv_ey;   // wave-uniform
    const float sz = (ez - pdz) * inv_ey;   // per-lane
    const float ddx = pdx - ex, ddz = pdz - ez;
    const float dxw = sqrtf(ddx * ddx + ey * ey + ddz * ddz) * fabsf(inv_ey);
    const float cb = pdx + 63.5f;           // wave-uniform
    const float ab = pdz + 63.5f;

    // Guard trim (conservative superset of nonzero steps), wave-uniform.
    float gc0, gc1, ga0, ga1;
    axis_interval(cb, sx, -1.0f, 128.0f, gc0, gc1);
    axis_interval(ab, sz, -1.0f, 128.0f, ga0, ga1);
    const float q_lo = fmaxf(fmaxf(gc0, ga0), 0.0f);
    const float q_hi = fminf(fminf(gc1, ga1), 127.0f);
    int q0, q1;
    if (q_lo <= q_hi + 0.5f) {
        q0 = max(0, (int)ceilf(q_lo) - 1);
        q1 = min(DVOL, (int)floorf(q_hi) + 2);
    } else { q0 = DVOL; q1 = 0; }           // miss lane: neutral for reduce
    int Q0 = wave_imin(q0);
    int Q1 = wave_imax(q1);
    Q0 = __builtin_amdgcn_readfirstlane(Q0);
    Q1 = __builtin_amdgcn_readfirstlane(Q1);

    // Build the wave's c-side table: entry e = p-Q0 for p in [Q0,Q1).
    // cf pre-biased +1 => [0,129]; trunc == floor; (c0+1) = (int)cf1 folds
    // into the word-row byte offset. t.x = packed f16 pair {lo:1-tc, hi:tc}.
    const int n = Q1 - Q0;
    for (int e = lane; e < n; e += 64) {
        const int p = Q0 + e;
        const float cf1 = __builtin_amdgcn_fmed3f(
            fmaf((float)p, sx, cb) + 1.0f, 0.0f, 129.0f);
        const int c0i = (int)cf1;                                // = c0+1
        const float tc = __builtin_amdgcn_fractf(cf1);
        uint2 t;
        t.x = (f16bits(tc) << 16) | f16bits(1.0f - tc);          // {1-tc, tc}
        t.y = (uint32_t)((p * IL_SLAB + c0i * IL_A) << 2);       // BYTE offset
        tab[wid][e] = t;
    }

    float acc = 0.0f;
    // af pre-biased +1: af0 = ab + 1 + Q0*sz
    const float af0 = fmaf((float)Q0, sz, ab + 1.0f);

    // ---- 2-deep pipelined batch loop: stages A/B, 16 loads in flight ----
    uint32_t tpA[BATCH]; float taA[BATCH]; uint2 wA[BATCH];
    uint32_t tpB[BATCH]; float taB[BATCH]; uint2 wB[BATCH];

    const int nb = (n > 0) ? (n >> 3) : 0;   // full batches of 8
    if (nb >= 2) {
        ISSUE(tpA, taA, wA, 0);
        int b = 0;
        for (; b + 2 < nb; b += 2) {
            ISSUE(tpB, taB, wB, b + 1);
            CONSUME(tpA, taA, wA);           // batch b
            ISSUE(tpA, taA, wA, b + 2);
            CONSUME(tpB, taB, wB);           // batch b+1
        }
        if (b + 1 < nb) {                    // two batches left: b, b+1
            ISSUE(tpB, taB, wB, b + 1);
            CONSUME(tpA, taA, wA);
            CONSUME(tpB, taB, wB);
        } else {                             // one batch left: b
            CONSUME(tpA, taA, wA);
        }
    } else if (nb == 1) {
        ISSUE(tpA, taA, wA, 0);
        CONSUME(tpA, taA, wA);
    }

    // ---- remainder (< 8 steps) ----
    for (int pe = nb << 3; pe < n; ++pe) {
        const uint2 t = tab[wid][pe];
        const float af1 = __builtin_amdgcn_fmed3f(
            fmaf((float)pe, sz, af0), 0.0f, 129.0f);
        const float ta = __builtin_amdgcn_fractf(af1);
        const uint32_t off = t.y + (((uint32_t)(int)af1) << 2);
        const uint2 w2 = *(const uint2*)((const char*)il + off);
        const half2_t tp = ash2(t.x);
        const float hx = __builtin_amdgcn_fdot2(ash2(w2.x), tp, 0.0f, false);
        const float hy = __builtin_amdgcn_fdot2(ash2(w2.y), tp, 0.0f, false);
        acc += fmaf(ta, hy - hx, hx);
    }

    if (store_ok) out[j * (RES * RES) + gi * RES + gj] = acc * (0.5f * dxw);
}

// ---------- fallback (R3-proven, used only if ws too small) ----------
__global__ __launch_bounds__(256) void proj_kernel_fb(
    const float* __restrict__ vol, const float* __restrict__ poses,
    const int* __restrict__ idx, float* __restrict__ out)
{
    const int gj = blockIdx.x * 64 + (threadIdx.x & 63);
    const int gi = blockIdx.y * 4 + (threadIdx.x >> 6);
    const int j  = blockIdx.z;
    if (blockIdx.x == 0 && blockIdx.y == 0 && j == 0 && threadIdx.x < NPROJ)
        out[OUT_PROJ + threadIdx.x] = (float)idx[threadIdx.x];
    if (gi >= RES || gj >= RES) return;
    const int pid = idx[j];
    const float ex = poses[pid*3+0], ey = poses[pid*3+1], ez = poses[pid*3+2];
    const float pdx = (float)gi - 89.5f, pdz = (float)gj - 89.5f;
    const float inv_ey = 1.0f / ey;
    const float sx = (ex - pdx) * inv_ey, sz = (ez - pdz) * inv_ey;
    const float ddx = pdx - ex, ddz = pdz - ez;
    const float dxw = sqrtf(ddx*ddx + ey*ey + ddz*ddz) * fabsf(inv_ey);
    const float cb = pdx + 63.5f, ab = pdz + 63.5f;
    float acc = 0.0f;
    for (int p = 0; p < DVOL; ++p) {
        const float cf = fmaf((float)p, sx, cb);
        const float af = fmaf((float)p, sz, ab);
        if (cf >= -1.0f && cf < 128.0f && af >= -1.0f && af < 128.0f) {
            const float c0f = floorf(cf), a0f = floorf(af);
            const float tc = cf - c0f, ta = af - a0f;
            const int c0 = (int)c0f, a0 = (int)a0f;
            const float wc0 = (c0 >= 0)   ? (1.0f - tc) : 0.0f;
            const float wc1 = (c0 <= 126) ? tc          : 0.0f;
            const float wa0 = (a0 >= 0)   ? (1.0f - ta) : 0.0f;
            const float wa1 = (a0 <= 126) ? ta          : 0.0f;
            const int c0c = c0 < 0 ? 0 : c0;
            const int c1c = c0 >= 127 ? 127 : c0 + 1;
            const int a0c = a0 < 0 ? 0 : a0;
            const int a1c = a0 >= 127 ? 127 : a0 + 1;
            const float w00 = wc0*wa0, w01 = wc0*wa1, w10 = wc1*wa0, w11 = wc1*wa1;
            const int b0 = (c0c << 14) + (p << 7);
            const int b1 = (c1c << 14) + (p << 7);
            float s = w00*vol[b0+a0c] + w01*vol[b0+a1c] + w10*vol[b1+a0c] + w11*vol[b1+a1c];
            if (p >= 1)
                s += w00*vol[b0+a0c-128] + w01*vol[b0+a1c-128]
                   + w10*vol[b1+a0c-128] + w11*vol[b1+a1c-128];
            acc += 0.5f * s;
        }
    }
    out[j * (RES * RES) + gi * RES + gj] = acc * dxw;
}

extern "C" void kernel_launch(void* const* d_in, const int* in_sizes, int n_in,
                              void* d_out, int out_size, void* d_ws, size_t ws_size,
                              hipStream_t stream) {
    const float* vol   = (const float*)d_in[0];
    const float* poses = (const float*)d_in[1];
    const int*   idx   = (const int*)d_in[2];
    float* out = (float*)d_out;

    if (ws_size >= (size_t)IL_TOT * sizeof(uint32_t)) {
        uint32_t* ilbuf = (uint32_t*)d_ws;
        dim3 pgrid(8, DVOL);                                        // (word-range, p)
        pad_kernel<<<pgrid, 128, 0, stream>>>(vol, ilbuf);
        dim3 grid(3 /*ceil(179/64)*/, 90 /*ceil(179/2)*/, NPROJ);   // R10/R15-proven
        proj_fast<<<grid, 128, 0, stream>>>(ilbuf, poses, idx, out);
    } else {
        dim3 grid(3, 45, NPROJ);
        proj_kernel_fb<<<grid, 256, 0, stream>>>(vol, poses, idx, out);
    }
}